// Round 1
// baseline (413.900 us; speedup 1.0000x reference)
//
#include <hip/hip_runtime.h>
#include <stdint.h>

// CenterNet postprocess: y_pred (32, 84, 128, 128) f32 -> (32, 100, 8) f32
// 3x3 NMS on 80 heatmap channels, per-batch exact top-100 (lax.top_k order),
// gather 4 coord channels, compute boxes.

#define NCLS   80
#define NCH    84
#define WD     128
#define HD     128
#define HWD    16384          // 128*128
#define NPB    (NCLS * HWD)   // 1310720 elements per batch
#define NBINS  4096
#define CAP    4096
#define MAXDET 100
#define NBATCH 32
#define ITEMS  16
#define TPB    256

// ws layout:
//   hist: NBATCH * NBINS u32   = 524288 B   @ 0
//   cnt : NBATCH u32           = 128 B      @ 524288
//   thr : NBATCH u32           = 128 B      @ 524416
//   cand: NBATCH * CAP u64     = 1048576 B  @ 524544
// total ~1.57 MB

__device__ __forceinline__ uint32_t fsort(float f) {
  uint32_t u = __float_as_uint(f);
  return u ^ ((u & 0x80000000u) ? 0xFFFFFFFFu : 0x80000000u);
}
__device__ __forceinline__ float funsort(uint32_t u) {
  uint32_t b = (u & 0x80000000u) ? (u ^ 0x80000000u) : ~u;
  return __uint_as_float(b);
}

// NMS'd value for flat element e = c*HWD + (h*WD + w) within one batch's
// heatmap block (channel-major, so address is simply hmb + e).
// Returns v if v is the max of its valid 3x3 window, else +/-0 (= v * 0.0f,
// matching the reference's hm * keep).
__device__ __forceinline__ float nms_val(const float* __restrict__ hmb, int e,
                                         bool& kept, float& v) {
  int sp = e & (HWD - 1);
  int h = sp >> 7, w = sp & (WD - 1);
  const float* p = hmb + e;
  v = p[0];
  float m = v;
  bool wl = (w > 0), wr = (w < WD - 1);
  if (wl) m = fmaxf(m, p[-1]);
  if (wr) m = fmaxf(m, p[1]);
  if (h > 0) {
    m = fmaxf(m, p[-WD]);
    if (wl) m = fmaxf(m, p[-WD - 1]);
    if (wr) m = fmaxf(m, p[-WD + 1]);
  }
  if (h < HD - 1) {
    m = fmaxf(m, p[WD]);
    if (wl) m = fmaxf(m, p[WD - 1]);
    if (wr) m = fmaxf(m, p[WD + 1]);
  }
  kept = (v == m);
  return kept ? v : 0.0f * v;
}

extern "C" __global__ __launch_bounds__(TPB)
void k_hist(const float* __restrict__ in, uint32_t* __restrict__ hist) {
  __shared__ uint32_t lh[NBINS];
  for (int i = threadIdx.x; i < NBINS; i += TPB) lh[i] = 0;
  __syncthreads();

  int b = blockIdx.y;
  const float* hmb = in + (size_t)b * NCH * HWD;
  int base = blockIdx.x * (TPB * ITEMS);
  uint32_t zp = 0, zn = 0;  // suppressed +0.0 / -0.0 counts (register-side)
  for (int it = 0; it < ITEMS; ++it) {
    int e = base + it * TPB + (int)threadIdx.x;
    bool kept; float v;
    (void)nms_val(hmb, e, kept, v);
    if (kept) {
      atomicAdd(&lh[fsort(v) >> 20], 1u);
    } else {
      if (__float_as_uint(v) >> 31) zn++; else zp++;
    }
  }
  // fsort(+0.0)>>20 == 2048, fsort(-0.0)>>20 == 2047
  if (zp) atomicAdd(&lh[2048], zp);
  if (zn) atomicAdd(&lh[2047], zn);
  __syncthreads();

  uint32_t* hb = hist + (size_t)b * NBINS;
  for (int i = threadIdx.x; i < NBINS; i += TPB) {
    uint32_t c = lh[i];
    if (c) atomicAdd(&hb[i], c);
  }
}

extern "C" __global__ __launch_bounds__(TPB)
void k_scan(const uint32_t* __restrict__ hist, uint32_t* __restrict__ thr) {
  int b = blockIdx.x;
  int t = threadIdx.x;
  const uint32_t* hb = hist + (size_t)b * NBINS;
  __shared__ uint32_t ssum[TPB];
  __shared__ uint32_t sthr;
  if (t == 0) sthr = 0;

  const int PER = NBINS / TPB;  // 16
  uint32_t loc[PER];
  uint32_t own = 0;
#pragma unroll
  for (int i = 0; i < PER; ++i) { loc[i] = hb[t * PER + i]; own += loc[i]; }
  ssum[t] = own;
  __syncthreads();
  if (t == 0) {  // exclusive suffix sums (from top bin down)
    uint32_t acc = 0;
    for (int j = TPB - 1; j >= 0; --j) { uint32_t v = ssum[j]; ssum[j] = acc; acc += v; }
  }
  __syncthreads();
  uint32_t above = ssum[t];
  if (above < MAXDET && above + own >= MAXDET) {  // crossing is in my 16 bins
    uint32_t cum = above;
    for (int i = PER - 1; i >= 0; --i) {
      cum += loc[i];
      if (cum >= MAXDET) { sthr = (uint32_t)(t * PER + i); break; }
    }
  }
  __syncthreads();
  if (t == 0) thr[b] = sthr;
}

extern "C" __global__ __launch_bounds__(TPB)
void k_collect(const float* __restrict__ in, const uint32_t* __restrict__ thr,
               uint64_t* __restrict__ cand, uint32_t* __restrict__ cnt) {
  int b = blockIdx.y;
  uint32_t uthr = thr[b] << 20;  // candidate iff fsort(nv) >= uthr
  const float* hmb = in + (size_t)b * NCH * HWD;
  int base = blockIdx.x * (TPB * ITEMS);
  for (int it = 0; it < ITEMS; ++it) {
    int e = base + it * TPB + (int)threadIdx.x;
    bool kept; float v;
    float nv = nms_val(hmb, e, kept, v);
    uint32_t u = fsort(nv);
    if (u >= uthr) {
      int sp = e & (HWD - 1);
      int c = e >> 14;
      uint32_t fi = (uint32_t)(sp * NCLS + c);  // (H,W,C)-flattened index
      uint32_t pos = atomicAdd(&cnt[b], 1u);
      if (pos < CAP)
        cand[(size_t)b * CAP + pos] = ((uint64_t)u << 32) | (uint32_t)(~fi);
    }
  }
}

extern "C" __global__ __launch_bounds__(TPB)
void k_final(const float* __restrict__ in, const uint64_t* __restrict__ cand,
             const uint32_t* __restrict__ cnt, float* __restrict__ out) {
  int b = blockIdx.x;
  __shared__ uint64_t sk[CAP];
  uint32_t n = cnt[b];
  if (n > CAP) n = CAP;
  uint32_t m = 128;
  while (m < n) m <<= 1;
  const uint64_t* cb = cand + (size_t)b * CAP;
  for (uint32_t i = threadIdx.x; i < m; i += TPB)
    sk[i] = (i < n) ? cb[i] : 0ull;  // key 0 sorts below all real keys
  __syncthreads();

  // bitonic sort, descending by (value, ~fi) -> value desc, index asc ties
  for (uint32_t k = 2; k <= m; k <<= 1) {
    for (uint32_t j = k >> 1; j > 0; j >>= 1) {
      for (uint32_t i = threadIdx.x; i < m; i += TPB) {
        uint32_t ixj = i ^ j;
        if (ixj > i) {
          uint64_t a = sk[i], c = sk[ixj];
          bool desc = (i & k) == 0;
          if (desc ? (a < c) : (a > c)) { sk[i] = c; sk[ixj] = a; }
        }
      }
      __syncthreads();
    }
  }

  if (threadIdx.x < MAXDET) {
    int j = threadIdx.x;
    uint64_t key = sk[j];
    uint32_t u = (uint32_t)(key >> 32);
    uint32_t fi = ~((uint32_t)key);
    float score = funsort(u);
    uint32_t c = fi % NCLS;
    uint32_t sp = (fi / NCLS) & (HWD - 1);  // mask guards pad keys only
    float xs = (float)(sp & (WD - 1));
    float ys = (float)(sp >> 7);
    const float* gp = in + ((size_t)b * NCH + NCLS) * HWD + sp;
    float g0 = gp[0], g1 = gp[HWD], g2 = gp[2 * HWD], g3 = gp[3 * HWD];
    float* o = out + ((size_t)b * MAXDET + j) * 8;
    o[0] = (float)(c + 1);
    o[1] = score;
    o[2] = (4.0f * xs - g0) * (1.0f / 512.0f);
    o[3] = (4.0f * ys - g1) * (1.0f / 512.0f);
    o[4] = (4.0f * xs + g2) * (1.0f / 512.0f);
    o[5] = (4.0f * ys + g3) * (1.0f / 512.0f);
    o[6] = ys;
    o[7] = xs;
  }
}

extern "C" void kernel_launch(void* const* d_in, const int* in_sizes, int n_in,
                              void* d_out, int out_size, void* d_ws, size_t ws_size,
                              hipStream_t stream) {
  (void)in_sizes; (void)n_in; (void)out_size; (void)ws_size;
  const float* in = (const float*)d_in[0];
  float* out = (float*)d_out;
  uint8_t* ws = (uint8_t*)d_ws;

  uint32_t* hist = (uint32_t*)(ws);
  uint32_t* cnt  = (uint32_t*)(ws + 524288);
  uint32_t* thr  = (uint32_t*)(ws + 524416);
  uint64_t* cand = (uint64_t*)(ws + 524544);

  // zero hist + cnt (+thr) each call — ws is not re-poisoned between replays
  hipMemsetAsync(ws, 0, 524544, stream);

  dim3 grid(NPB / (TPB * ITEMS), NBATCH);  // (320, 32)
  k_hist<<<grid, TPB, 0, stream>>>(in, hist);
  k_scan<<<NBATCH, TPB, 0, stream>>>(hist, thr);
  k_collect<<<grid, TPB, 0, stream>>>(in, thr, cand, cnt);
  k_final<<<NBATCH, TPB, 0, stream>>>(in, cand, cnt, out);
}

// Round 2
// 376.064 us; speedup vs baseline: 1.1006x; 1.1006x over previous
//
#include <hip/hip_runtime.h>
#include <stdint.h>

// CenterNet postprocess: y_pred (32, 84, 128, 128) f32 -> (32, 100, 8) f32
// Pass1: fused single-load NMS + per-batch 4096-bin histogram + candidate
//        collection above a conservative static threshold.
// Scan:  exact per-batch threshold bin from histogram; flags fallback if the
//        static threshold was too high (never for this data).
// Fallback: exact re-collect (early-exits when not needed).
// Final: bitonic sort candidates, top-100, gather coords, emit boxes.

#define NCLS   80
#define NCH    84
#define WD     128
#define HD     128
#define HWD    16384
#define NPB    (NCLS * HWD)
#define NBINS  4096
#define CAP    4096
#define MAXDET 100
#define NBATCH 32
#define NEGINF (-__builtin_huge_valf())

// static pre-threshold: bin of value 3.0 (fsort(3.0)>>20 == 0xC04 == 3076).
// True top-100 threshold for N(0,1) data at 1.31M/batch is ~3.79 (bin 3079).
#define USTATIC_BIN 3076u
#define USTATIC_U   (USTATIC_BIN << 20)

// ws layout (bytes):
#define HIST_OFF 0          // 32*4096*4 = 524288
#define CNT_OFF  524288     // 32*4 = 128
#define NEED_OFF 524416     // 32*4 = 128
#define THR_OFF  524544     // 32*4 = 128
#define CAND_OFF 524672     // 32*4096*8 = 1048576
#define ZERO_BYTES 524544   // hist + cnt + need

__device__ __forceinline__ uint32_t fsort(float f) {
  uint32_t u = __float_as_uint(f);
  return u ^ ((u & 0x80000000u) ? 0xFFFFFFFFu : 0x80000000u);
}
__device__ __forceinline__ float funsort(uint32_t u) {
  uint32_t b = (u & 0x80000000u) ? (u ^ 0x80000000u) : ~u;
  return __uint_as_float(b);
}

__device__ __forceinline__ float4 hmax4(float4 w, int l31) {
  float left  = __shfl_up(w.w, 1);
  float right = __shfl_down(w.x, 1);
  if (l31 == 0)  left  = NEGINF;
  if (l31 == 31) right = NEGINF;
  float4 h;
  h.x = fmaxf(fmaxf(left, w.x), w.y);
  h.y = fmaxf(fmaxf(w.x, w.y), w.z);
  h.z = fmaxf(fmaxf(w.y, w.z), w.w);
  h.w = fmaxf(fmaxf(w.z, w.w), right);
  return h;
}

// ---------------- pass 1: NMS + histogram + static-threshold collect --------
// 1280 blocks x 256 threads. Each 32-lane half-wave sweeps a 32-row chunk of
// one (b,c) plane; 8 strips per block, 40 blocks per batch.
extern "C" __global__ __launch_bounds__(256)
void k_pass1(const float* __restrict__ in, uint32_t* __restrict__ hist,
             uint64_t* __restrict__ cand, uint32_t* __restrict__ cnt) {
  __shared__ uint32_t lh[NBINS];
  for (int i = threadIdx.x; i < NBINS; i += 256) lh[i] = 0;
  __syncthreads();

  const int bid  = blockIdx.x;
  const int b    = bid / 40;
  const int sg   = (bid % 40) * 8 + (threadIdx.x >> 5);  // strip 0..319
  const int c    = sg >> 2;
  const int r0   = (sg & 3) * 32;
  const int lane = threadIdx.x & 63;
  const int l31  = threadIdx.x & 31;
  const float* pp = in + ((size_t)b * NCH + c) * HWD + 4 * l31;

  const float4 neg4 = make_float4(NEGINF, NEGINF, NEGINF, NEGINF);
  uint32_t zp = 0, zn = 0;

#define LDROW(r) (*reinterpret_cast<const float4*>(pp + (size_t)(r) * WD))

  float4 hp = (r0 > 0) ? hmax4(LDROW(r0 - 1), l31) : neg4;
  float4 vc = LDROW(r0);
  float4 hc = hmax4(vc, l31);
  float4 vn = LDROW(r0 + 1);  // r0+1 <= 97 < 128 always

  uint32_t* hb = hist + (size_t)b * NBINS;
  uint64_t* cb = cand + (size_t)b * CAP;

  for (int r = r0; r < r0 + 32; ++r) {
    float4 vf;
    int r2 = r + 2;
    bool has2 = (r2 <= r0 + 32) && (r2 < HD);
    if (has2) vf = LDROW(r2);

    float4 hn = (r + 1 < HD) ? hmax4(vn, l31) : neg4;

#define PROC(vi, hpi, hci, hni, col)                                      \
    {                                                                     \
      float m_ = fmaxf(fmaxf(hpi, hci), hni);                             \
      if (vi == m_) {                                                     \
        uint32_t u_ = fsort(vi);                                          \
        atomicAdd(&lh[u_ >> 20], 1u);                                     \
        if (u_ >= USTATIC_U) {                                            \
          uint32_t fi_ = (uint32_t)(((r * WD) + (col)) * NCLS + c);       \
          uint32_t pos_ = atomicAdd(&cnt[b], 1u);                         \
          if (pos_ < CAP)                                                 \
            cb[pos_] = ((uint64_t)u_ << 32) | (uint32_t)(~fi_);           \
        }                                                                 \
      } else if (__float_as_uint(vi) >> 31) zn++; else zp++;              \
    }

    PROC(vc.x, hp.x, hc.x, hn.x, 4 * l31 + 0)
    PROC(vc.y, hp.y, hc.y, hn.y, 4 * l31 + 1)
    PROC(vc.z, hp.z, hc.z, hn.z, 4 * l31 + 2)
    PROC(vc.w, hp.w, hc.w, hn.w, 4 * l31 + 3)
#undef PROC

    hp = hc; hc = hn; vc = vn; vn = vf;
  }
#undef LDROW

  // reduce suppressed-zero counts across the wave, one atomic per wave
  for (int off = 32; off; off >>= 1) {
    zp += __shfl_down(zp, off);
    zn += __shfl_down(zn, off);
  }
  if (lane == 0) {
    if (zp) atomicAdd(&lh[2048], zp);  // +0.0 bin
    if (zn) atomicAdd(&lh[2047], zn);  // -0.0 bin
  }
  __syncthreads();

  for (int i = threadIdx.x; i < NBINS; i += 256) {
    uint32_t v = lh[i];
    if (v) atomicAdd(&hb[i], v);
  }
}

// ---------------- scan: exact threshold bin + fallback flag -----------------
extern "C" __global__ __launch_bounds__(256)
void k_scan(const uint32_t* __restrict__ hist, uint32_t* __restrict__ cnt,
            uint32_t* __restrict__ thr, uint32_t* __restrict__ need) {
  int b = blockIdx.x;
  int t = threadIdx.x;
  const uint32_t* hb = hist + (size_t)b * NBINS;
  __shared__ uint32_t ssum[256];
  __shared__ uint32_t sthr;
  if (t == 0) sthr = 0;

  const int PER = NBINS / 256;  // 16
  uint32_t loc[PER];
  uint32_t own = 0;
#pragma unroll
  for (int i = 0; i < PER; ++i) { loc[i] = hb[t * PER + i]; own += loc[i]; }
  ssum[t] = own;
  __syncthreads();
  if (t == 0) {  // exclusive suffix sums from the top bin down
    uint32_t acc = 0;
    for (int j = 255; j >= 0; --j) { uint32_t v = ssum[j]; ssum[j] = acc; acc += v; }
  }
  __syncthreads();
  uint32_t above = ssum[t];
  if (above < MAXDET && above + own >= MAXDET) {
    uint32_t cum = above;
    for (int i = PER - 1; i >= 0; --i) {
      cum += loc[i];
      if (cum >= MAXDET) { sthr = (uint32_t)(t * PER + i); break; }
    }
  }
  __syncthreads();
  if (t == 0) {
    thr[b] = sthr;
    uint32_t nd = (sthr < USTATIC_BIN) || (cnt[b] > CAP);
    need[b] = nd;
    if (nd) cnt[b] = 0;  // fallback will re-collect exactly
  }
}

// ---------------- fallback exact collect (normally a no-op) -----------------
extern "C" __global__ __launch_bounds__(256)
void k_fallback(const float* __restrict__ in, const uint32_t* __restrict__ thr,
                const uint32_t* __restrict__ need, uint64_t* __restrict__ cand,
                uint32_t* __restrict__ cnt) {
  int b = blockIdx.y;
  if (!need[b]) return;
  uint32_t uthr = thr[b] << 20;
  const float* hmb = in + (size_t)b * NCH * HWD;
  int base = blockIdx.x * 32768;
  for (int it = 0; it < 128; ++it) {
    int e = base + it * 256 + (int)threadIdx.x;
    int sp = e & (HWD - 1);
    int h = sp >> 7, w = sp & (WD - 1);
    const float* p = hmb + e;
    float v = p[0];
    float m = v;
    bool wl = (w > 0), wr = (w < WD - 1);
    if (wl) m = fmaxf(m, p[-1]);
    if (wr) m = fmaxf(m, p[1]);
    if (h > 0) {
      m = fmaxf(m, p[-WD]);
      if (wl) m = fmaxf(m, p[-WD - 1]);
      if (wr) m = fmaxf(m, p[-WD + 1]);
    }
    if (h < HD - 1) {
      m = fmaxf(m, p[WD]);
      if (wl) m = fmaxf(m, p[WD - 1]);
      if (wr) m = fmaxf(m, p[WD + 1]);
    }
    bool kept = (v == m);
    float nv = kept ? v : 0.0f * v;
    uint32_t u = fsort(nv);
    if (u >= uthr) {
      int cch = e >> 14;
      uint32_t fi = (uint32_t)(sp * NCLS + cch);
      uint32_t pos = atomicAdd(&cnt[b], 1u);
      if (pos < CAP)
        cand[(size_t)b * CAP + pos] = ((uint64_t)u << 32) | (uint32_t)(~fi);
    }
  }
}

// ---------------- final: sort, select, gather, emit -------------------------
extern "C" __global__ __launch_bounds__(1024)
void k_final(const float* __restrict__ in, const uint64_t* __restrict__ cand,
             const uint32_t* __restrict__ cnt, float* __restrict__ out) {
  int b = blockIdx.x;
  __shared__ uint64_t sk[CAP];
  uint32_t n = cnt[b];
  if (n > CAP) n = CAP;
  uint32_t m = 128;
  while (m < n) m <<= 1;
  const uint64_t* cb = cand + (size_t)b * CAP;
  for (uint32_t i = threadIdx.x; i < m; i += 1024)
    sk[i] = (i < n) ? cb[i] : 0ull;
  __syncthreads();

  for (uint32_t k = 2; k <= m; k <<= 1) {
    for (uint32_t j = k >> 1; j > 0; j >>= 1) {
      for (uint32_t i = threadIdx.x; i < m; i += 1024) {
        uint32_t ixj = i ^ j;
        if (ixj > i && ixj < m) {
          uint64_t a = sk[i], c = sk[ixj];
          bool desc = (i & k) == 0;
          if (desc ? (a < c) : (a > c)) { sk[i] = c; sk[ixj] = a; }
        }
      }
      __syncthreads();
    }
  }

  if (threadIdx.x < MAXDET) {
    int j = threadIdx.x;
    uint64_t key = sk[j];
    uint32_t u = (uint32_t)(key >> 32);
    uint32_t fi = ~((uint32_t)key);
    float score = funsort(u);
    uint32_t c = fi % NCLS;
    uint32_t sp = (fi / NCLS) & (HWD - 1);
    float xs = (float)(sp & (WD - 1));
    float ys = (float)(sp >> 7);
    const float* gp = in + ((size_t)b * NCH + NCLS) * HWD + sp;
    float g0 = gp[0], g1 = gp[HWD], g2 = gp[2 * HWD], g3 = gp[3 * HWD];
    float* o = out + ((size_t)b * MAXDET + j) * 8;
    o[0] = (float)(c + 1);
    o[1] = score;
    o[2] = (4.0f * xs - g0) * (1.0f / 512.0f);
    o[3] = (4.0f * ys - g1) * (1.0f / 512.0f);
    o[4] = (4.0f * xs + g2) * (1.0f / 512.0f);
    o[5] = (4.0f * ys + g3) * (1.0f / 512.0f);
    o[6] = ys;
    o[7] = xs;
  }
}

extern "C" void kernel_launch(void* const* d_in, const int* in_sizes, int n_in,
                              void* d_out, int out_size, void* d_ws, size_t ws_size,
                              hipStream_t stream) {
  (void)in_sizes; (void)n_in; (void)out_size; (void)ws_size;
  const float* in = (const float*)d_in[0];
  float* out = (float*)d_out;
  uint8_t* ws = (uint8_t*)d_ws;

  uint32_t* hist = (uint32_t*)(ws + HIST_OFF);
  uint32_t* cnt  = (uint32_t*)(ws + CNT_OFF);
  uint32_t* need = (uint32_t*)(ws + NEED_OFF);
  uint32_t* thr  = (uint32_t*)(ws + THR_OFF);
  uint64_t* cand = (uint64_t*)(ws + CAND_OFF);

  hipMemsetAsync(ws, 0, ZERO_BYTES, stream);

  k_pass1<<<1280, 256, 0, stream>>>(in, hist, cand, cnt);
  k_scan<<<NBATCH, 256, 0, stream>>>(hist, cnt, thr, need);
  k_fallback<<<dim3(40, NBATCH), 256, 0, stream>>>(in, thr, need, cand, cnt);
  k_final<<<NBATCH, 1024, 0, stream>>>(in, cand, cnt, out);
}